// Round 2
// baseline (1210.146 us; speedup 1.0000x reference)
//
#include <hip/hip_runtime.h>
#include <math.h>

#define NTOK   2048
#define D      512
#define NV     100000

typedef __attribute__((ext_vector_type(8)))  short bf16x8;
typedef __attribute__((ext_vector_type(16))) float f32x16;

// ---- workspace layout (bytes) ----
#define WS_FRAGS 0u          // 4 segs * 2048 rows * 512 * 2B = 8,388,608
#define WS_LISTS 8388608u    // 4 * 2048 * 4B
#define WS_ACC   8421376u    // 4 * 2049 * 4B = 32784  (zeroed each call, + cursors)
#define WS_CUR   8454160u    // 4 * 4
#define WS_PAD   8454176u    // 4 * 4
#define WS_CL    8454192u    // 2048 * 3 * 4B
#define WS_TGT   8478768u    // 2048 * 4B

__device__ __forceinline__ int cluster_of(int t){
  return (t < 10000) ? 0 : (t < 20000) ? 1 : (t < 50000) ? 2 : 3;
}
__device__ __forceinline__ bool is_root(int c){
  return c==5 || c==17 || c==123 || c==10005 || c==20007 || c==50011;
}
// f32 -> bf16 round-to-nearest-even (manual: no hip_bf16 API dependence)
__device__ __forceinline__ unsigned short f2bf(float f){
  unsigned int u = __float_as_uint(f);
  u += 0x7fffu + ((u >> 16) & 1u);
  return (unsigned short)(u >> 16);
}

// ---------------------------------------------------------------------------
// K1: per-token cluster logits (3 dots) + exact-f32 target logit. 1 wave/token.
// ---------------------------------------------------------------------------
__global__ void k_token_logits(const float* __restrict__ hidden,
                               const float* __restrict__ weight,
                               const float* __restrict__ bias,
                               const float* __restrict__ cw,
                               const float* __restrict__ cb,
                               const int*   __restrict__ target,
                               float* __restrict__ cl_out,   // [2048][3]
                               float* __restrict__ tgt_out)  // [2048]
{
  int wave = threadIdx.x >> 6;
  int lane = threadIdx.x & 63;
  int n = blockIdx.x * 4 + wave;
  if (n >= NTOK) return;
  const float* h = hidden + (size_t)n * D + lane * 8;
  int t = target[n];
  const float* wt = weight + (size_t)t * D + lane * 8;
  float hv[8];
  #pragma unroll
  for (int i = 0; i < 8; ++i) hv[i] = h[i];
  float acc[4] = {0.f, 0.f, 0.f, 0.f};
  #pragma unroll
  for (int j = 0; j < 3; ++j){
    const float* cwj = cw + j * D + lane * 8;
    float s = 0.f;
    #pragma unroll
    for (int i = 0; i < 8; ++i) s += hv[i] * cwj[i];
    acc[j] = s;
  }
  {
    float s = 0.f;
    #pragma unroll
    for (int i = 0; i < 8; ++i) s += hv[i] * wt[i];
    acc[3] = s;
  }
  #pragma unroll
  for (int m = 1; m < 64; m <<= 1){
    #pragma unroll
    for (int j = 0; j < 4; ++j) acc[j] += __shfl_xor(acc[j], m, 64);
  }
  if (lane == 0){
    cl_out[n*3+0] = acc[0] + cb[0];
    cl_out[n*3+1] = acc[1] + cb[1];
    cl_out[n*3+2] = acc[2] + cb[2];
    float tg = acc[3] + bias[t];
    if (is_root(t)) tg = -INFINITY;   // masked column: lp = -inf
    tgt_out[n] = tg;
  }
}

// ---------------------------------------------------------------------------
// K2: build per-segment token lists. seg0 = identity; tails via atomic cursor.
// ---------------------------------------------------------------------------
__global__ void k_build_lists(const int* __restrict__ target,
                              int* __restrict__ lists, int* __restrict__ cursors)
{
  int n = blockIdx.x * blockDim.x + threadIdx.x;
  if (n >= NTOK) return;
  lists[n] = n;  // seg 0 identity
  int c = cluster_of(target[n]);
  if (c > 0){
    int pos = atomicAdd(cursors + c, 1);
    lists[c * 2048 + pos] = n;
  }
}

// ---------------------------------------------------------------------------
// K3: pad lists to multiples of 256 with sentinel token (=NTOK), write counts.
// ---------------------------------------------------------------------------
__global__ void k_pad_lists(int* __restrict__ lists, const int* __restrict__ cursors,
                            int* __restrict__ padded)
{
  if (threadIdx.x == 0) padded[0] = NTOK;
  for (int s = 1; s < 4; ++s){
    int c = cursors[s];
    int p = (c + 255) & ~255;
    if (threadIdx.x == 0) padded[s] = p;
    for (int i = c + threadIdx.x; i < p; i += blockDim.x)
      lists[s * 2048 + i] = NTOK;   // sentinel -> dummy acc slot
  }
}

// ---------------------------------------------------------------------------
// K4: build bf16 A-fragments in MFMA-native layout per segment.
// slot elem offset = ((mf*32 + ks)*64 + lane)*8 ; row = mf*32+(lane&31),
// k = ks*16 + (lane>>5)*8 + j  (same k-convention used for B at MFMA time).
// ---------------------------------------------------------------------------
__global__ void k_build_frags(const float* __restrict__ hidden,
                              const int*   __restrict__ lists,
                              const int*   __restrict__ padded,
                              unsigned short* __restrict__ frags)
{
  int tg   = blockIdx.x * 256 + threadIdx.x;   // [0, 4*131072)
  int seg  = tg >> 17;
  int s    = tg & 131071;
  int lane = s & 63;
  int ks   = (s >> 6) & 31;
  int mf   = s >> 11;
  int row  = mf * 32 + (lane & 31);
  if (row >= padded[seg]) return;
  int token = lists[seg * 2048 + row];
  unsigned int w[4];
  if (token < NTOK){
    const float* h = hidden + (size_t)token * D + ks * 16 + (lane >> 5) * 8;
    #pragma unroll
    for (int i = 0; i < 4; ++i){
      unsigned short lo = f2bf(h[2*i]);
      unsigned short hi = f2bf(h[2*i+1]);
      w[i] = (unsigned int)lo | ((unsigned int)hi << 16);
    }
  } else {
    w[0] = w[1] = w[2] = w[3] = 0u;  // pad rows: zero hidden
  }
  size_t off = ((size_t)seg * 2048 * 512) + (((size_t)(mf * 32 + ks)) * 64 + lane) * 8;
  uint4 val; val.x = w[0]; val.y = w[1]; val.z = w[2]; val.w = w[3];
  *(uint4*)(frags + off) = val;
}

// ---------------------------------------------------------------------------
// K5: the Σexp GEMM. Each WG owns a 64-col strip of weight (bf16 in LDS,
// XOR-swizzled, full K=512), loops over segment rows in 256-row tiles
// (4 waves x 64 rows x 64 cols, mfma_f32_32x32x16_bf16, 2x2 frags/wave).
// Epilogue: exp(logit+bias) with bias=-inf encoding col-invalid/root masking,
// butterfly row-sum over 32 lanes, one atomicAdd per row per WG.
// ---------------------------------------------------------------------------
__device__ __forceinline__ void epi(const f32x16& aA, const f32x16& aB,
                                    float b0v, float b1v, int rbase,
                                    int hi, int laneM,
                                    const int* __restrict__ lists_seg,
                                    float* __restrict__ acc_seg)
{
  float ev[16];
  #pragma unroll
  for (int r = 0; r < 16; ++r)
    ev[r] = __expf(aA[r] + b0v) + __expf(aB[r] + b1v);
  #pragma unroll
  for (int m = 1; m < 32; m <<= 1){
    #pragma unroll
    for (int r = 0; r < 16; ++r) ev[r] += __shfl_xor(ev[r], m, 64);
  }
  if (laneM == 0){
    #pragma unroll
    for (int r = 0; r < 16; ++r){
      int row = rbase + (r & 3) + 8 * (r >> 2) + 4 * hi;  // verified C/D layout
      atomicAdd(acc_seg + lists_seg[row], ev[r]);
    }
  }
}

__global__ __launch_bounds__(256, 2)
void k_gemm(const unsigned short* __restrict__ frags,
            const float* __restrict__ weight,
            const float* __restrict__ bias,
            const int*   __restrict__ lists,
            const int*   __restrict__ padded,
            float* __restrict__ acc_out)       // [4][2049]
{
  __shared__ unsigned short Bs[64 * 512];      // 64 KB, swizzled [col][k]

  int bid = blockIdx.x;
  int seg, strip0, colstart, colend;
  if      (bid < 157){ seg = 0; strip0 = 0;   colstart = 0;     colend = 10000;  }
  else if (bid < 314){ seg = 1; strip0 = 157; colstart = 10000; colend = 20000;  }
  else if (bid < 783){ seg = 2; strip0 = 314; colstart = 20000; colend = 50000;  }
  else               { seg = 3; strip0 = 783; colstart = 50000; colend = 100000; }
  int col_base = colstart + (bid - strip0) * 64;
  int col_end  = min(col_base + 64, colend);

  // ---- load B strip: 64 cols x 512 k, f32 -> bf16, swizzled LDS ----
  for (int it = 0; it < 32; ++it){
    int id  = it * 256 + threadIdx.x;
    int col = id >> 7;           // 0..63
    int kq  = (id & 127) * 4;    // 0..508 (f32 elems)
    int cg  = col_base + col;
    float4 v = make_float4(0.f, 0.f, 0.f, 0.f);
    if (cg < col_end) v = *(const float4*)(weight + (size_t)cg * D + kq);
    unsigned int lo = (unsigned int)f2bf(v.x) | ((unsigned int)f2bf(v.y) << 16);
    unsigned int hi = (unsigned int)f2bf(v.z) | ((unsigned int)f2bf(v.w) << 16);
    int byteoff = col * 1024 + ((kq * 2) ^ ((col & 7) << 4));
    uint2 pk; pk.x = lo; pk.y = hi;
    *(uint2*)((char*)Bs + byteoff) = pk;
  }
  __syncthreads();

  int wave  = threadIdx.x >> 6;
  int lane  = threadIdx.x & 63;
  int laneM = lane & 31;
  int hi    = lane >> 5;
  int M = padded[seg];
  const unsigned short* fseg = frags + (size_t)seg * 2048 * 512;
  const int*  lists_seg = lists + seg * 2048;
  float*      acc_seg   = acc_out + seg * 2049;

  // per-lane bias (also encodes masking: invalid col or root -> -inf)
  int cg0 = col_base + laneM, cg1 = col_base + 32 + laneM;
  float b0v = (cg0 < col_end && !is_root(cg0)) ? bias[cg0] : -INFINITY;
  float b1v = (cg1 < col_end && !is_root(cg1)) ? bias[cg1] : -INFINITY;

  int xorterm = (laneM & 7) << 4;
  const char* bsc = (const char*)Bs;
  int bbase0 = laneM * 1024;
  int bbase1 = (32 + laneM) * 1024;

  for (int m0 = 0; m0 < M; m0 += 256){
    int r0 = m0 + wave * 64;
    f32x16 acc00, acc01, acc10, acc11;
    #pragma unroll
    for (int i = 0; i < 16; ++i){ acc00[i]=0.f; acc01[i]=0.f; acc10[i]=0.f; acc11[i]=0.f; }

    const unsigned short* pa0 = fseg + (size_t)(r0 >> 5) * 16384 + (size_t)lane * 8;
    const unsigned short* pa1 = pa0 + 16384;

    #pragma unroll 4
    for (int ks = 0; ks < 32; ++ks){
      bf16x8 a0 = *(const bf16x8*)(pa0 + ks * 512);
      bf16x8 a1 = *(const bf16x8*)(pa1 + ks * 512);
      int kb = (ks * 32 + hi * 16) ^ xorterm;
      bf16x8 b0 = *(const bf16x8*)(bsc + bbase0 + kb);
      bf16x8 b1 = *(const bf16x8*)(bsc + bbase1 + kb);
      acc00 = __builtin_amdgcn_mfma_f32_32x32x16_bf16(a0, b0, acc00, 0, 0, 0);
      acc01 = __builtin_amdgcn_mfma_f32_32x32x16_bf16(a0, b1, acc01, 0, 0, 0);
      acc10 = __builtin_amdgcn_mfma_f32_32x32x16_bf16(a1, b0, acc10, 0, 0, 0);
      acc11 = __builtin_amdgcn_mfma_f32_32x32x16_bf16(a1, b1, acc11, 0, 0, 0);
    }
    epi(acc00, acc01, b0v, b1v, r0,      hi, laneM, lists_seg, acc_seg);
    epi(acc10, acc11, b0v, b1v, r0 + 32, hi, laneM, lists_seg, acc_seg);
  }
}

// ---------------------------------------------------------------------------
// K6: finalize NLL per token.
// ---------------------------------------------------------------------------
__global__ void k_finalize(const float* __restrict__ accs,   // [4][2049]
                           const float* __restrict__ cl,     // [2048][3]
                           const float* __restrict__ tgt,
                           const int*   __restrict__ target,
                           float* __restrict__ out)
{
  int n = blockIdx.x * blockDim.x + threadIdx.x;
  if (n >= NTOK) return;
  int c = cluster_of(target[n]);
  float e0 = __expf(cl[n*3+0]), e1 = __expf(cl[n*3+1]), e2 = __expf(cl[n*3+2]);
  float head_lse = __logf(accs[n] + e0 + e1 + e2);
  float nll;
  if (c == 0){
    nll = head_lse - tgt[n];
  } else {
    float tail_lse = __logf(accs[c * 2049 + n]);
    // head col (HEAD_SIZE - c) == cluster row (3 - c)
    nll = head_lse + tail_lse - cl[n*3 + (3 - c)] - tgt[n];
  }
  out[n] = nll;
}

extern "C" void kernel_launch(void* const* d_in, const int* in_sizes, int n_in,
                              void* d_out, int out_size, void* d_ws, size_t ws_size,
                              hipStream_t stream)
{
  (void)in_sizes; (void)n_in; (void)out_size; (void)ws_size;
  const float* hidden = (const float*)d_in[0];
  const float* weight = (const float*)d_in[1];
  const float* bias   = (const float*)d_in[2];
  const float* cw     = (const float*)d_in[3];
  const float* cb     = (const float*)d_in[4];
  const int*   target = (const int*)d_in[5];
  float* out = (float*)d_out;
  char*  ws  = (char*)d_ws;

  unsigned short* frags = (unsigned short*)(ws + WS_FRAGS);
  int*   lists   = (int*)(ws + WS_LISTS);
  float* acc     = (float*)(ws + WS_ACC);
  int*   cursors = (int*)(ws + WS_CUR);
  int*   padded  = (int*)(ws + WS_PAD);
  float* cl      = (float*)(ws + WS_CL);
  float* tgt     = (float*)(ws + WS_TGT);

  // zero acc (4x2049 f32) + cursors (4 int) in one async memset
  hipMemsetAsync(ws + WS_ACC, 0, (WS_CUR + 16u) - WS_ACC, stream);

  k_token_logits<<<512, 256, 0, stream>>>(hidden, weight, bias, cw, cb, target, cl, tgt);
  k_build_lists <<<8,   256, 0, stream>>>(target, lists, cursors);
  k_pad_lists   <<<1,   256, 0, stream>>>(lists, cursors, padded);
  k_build_frags <<<2048,256, 0, stream>>>(hidden, lists, padded, frags);
  k_gemm        <<<1565,256, 0, stream>>>(frags, weight, bias, lists, padded, acc);
  k_finalize    <<<8,   256, 0, stream>>>(acc, cl, tgt, target, out);
}